// Round 1
// baseline (6158.145 us; speedup 1.0000x reference)
//
#include <hip/hip_runtime.h>
#include <hip/hip_bf16.h>
#include <math.h>

// ---------------------------------------------------------------------------
// GATv2 x2 + global_add_pool + MLP head, fp32, gather-CSR online-softmax conv
// ---------------------------------------------------------------------------

__global__ void k_deg(const int* __restrict__ dst, int E, int* __restrict__ deg) {
    int e = blockIdx.x * blockDim.x + threadIdx.x;
    if (e < E) atomicAdd(&deg[dst[e]], 1);
}

// single-block exclusive scan: row_ptr[N+1], woff[i] = row_ptr[i]
__global__ void k_scan(const int* __restrict__ deg, int N,
                       int* __restrict__ row_ptr, int* __restrict__ woff) {
    __shared__ int buf[1024];
    __shared__ int carry;
    if (threadIdx.x == 0) carry = 0;
    __syncthreads();
    for (int base = 0; base < N; base += 1024) {
        int i = base + (int)threadIdx.x;
        int v = (i < N) ? deg[i] : 0;
        buf[threadIdx.x] = v;
        __syncthreads();
        for (int off = 1; off < 1024; off <<= 1) {
            int t = (threadIdx.x >= (unsigned)off) ? buf[threadIdx.x - off] : 0;
            __syncthreads();
            buf[threadIdx.x] += t;
            __syncthreads();
        }
        int incl = buf[threadIdx.x] + carry;
        if (i < N) { row_ptr[i + 1] = incl; woff[i] = incl - v; }
        if (base == 0 && threadIdx.x == 0) row_ptr[0] = 0;
        __syncthreads();
        if (threadIdx.x == 1023) carry = incl;
        __syncthreads();
    }
}

__global__ void k_scatter(const int* __restrict__ dst, int E,
                          int* __restrict__ woff, int* __restrict__ cidx) {
    int e = blockIdx.x * blockDim.x + threadIdx.x;
    if (e < E) { int p = atomicAdd(&woff[dst[e]], 1); cidx[p] = e; }
}

// per-node mean of incoming edge attrs (0 if none): one wave per node, lanes 0..31 = k
__global__ void k_ealoop(const float* __restrict__ ea, const int* __restrict__ cidx,
                         const int* __restrict__ row_ptr, int N,
                         float* __restrict__ ealoop) {
    int w = (blockIdx.x * blockDim.x + threadIdx.x) >> 6;
    int lane = threadIdx.x & 63;
    if (w >= N) return;
    int beg = row_ptr[w], end = row_ptr[w + 1];
    if (lane < 32) {
        float s = 0.f;
        for (int i = beg; i < end; ++i) {
            int e = cidx[i];
            s += ea[(size_t)e * 32 + lane];
        }
        int c = end - beg;
        ealoop[(size_t)w * 32 + lane] = s / (float)(c > 0 ? c : 1);
    }
}

// out[n][col] = in[n][0:128] . W[:,col] + b[col], W column held in 128 VGPRs.
// grid.y chunks: [0,HC/64) -> (Wl,bl,outl); [HC/64, 2*HC/64) -> (Wr,br,outr)
template <int HC>
__global__ void k_xw(const float* __restrict__ in, int N,
                     const float* __restrict__ Wl, const float* __restrict__ bl,
                     const float* __restrict__ Wr, const float* __restrict__ br,
                     float* __restrict__ outl, float* __restrict__ outr) {
    constexpr int NCH = HC / 64;
    int chunk = blockIdx.y;
    const float* W;
    const float* b;
    float* out;
    int cc;
    if (chunk < NCH) { W = Wl; b = bl; out = outl; cc = chunk; }
    else             { W = Wr; b = br; out = outr; cc = chunk - NCH; }
    const int lane = threadIdx.x & 63;
    const int col = cc * 64 + lane;
    float wreg[128];
#pragma unroll
    for (int k = 0; k < 128; ++k) wreg[k] = W[k * HC + col];
    const float breg = b[col];
    const int wid = (blockIdx.x * blockDim.x + threadIdx.x) >> 6;
    const int nw = (gridDim.x * blockDim.x) >> 6;
    for (int n = wid; n < N; n += nw) {
        const float4* xp = (const float4*)(in + (size_t)n * 128);
        float a0 = 0.f, a1 = 0.f, a2 = 0.f, a3 = 0.f;
#pragma unroll
        for (int q = 0; q < 32; ++q) {
            float4 v = xp[q];
            a0 += v.x * wreg[4 * q + 0];
            a1 += v.y * wreg[4 * q + 1];
            a2 += v.z * wreg[4 * q + 2];
            a3 += v.w * wreg[4 * q + 3];
        }
        out[(size_t)n * HC + col] = (a0 + a1) + (a2 + a3) + breg;
    }
}

// GATv2 conv, gather-CSR, online softmax. One wave per node, lane = channel c.
// We[k][h*64+lane] in registers; ea via wave-uniform float4 broadcast loads.
template <int H, bool RELU>
__global__ void k_conv(const float* __restrict__ xl, const float* __restrict__ xr,
                       const float* __restrict__ ealoop, const float* __restrict__ ea,
                       const int* __restrict__ src, const int* __restrict__ cidx,
                       const int* __restrict__ row_ptr,
                       const float* __restrict__ We, const float* __restrict__ att,
                       const float* __restrict__ bias, int Nn,
                       float* __restrict__ out) {
    constexpr int HC = H * 64;
    const int lane = threadIdx.x & 63;
    const int wid = (blockIdx.x * blockDim.x + threadIdx.x) >> 6;
    const int nw = (gridDim.x * blockDim.x) >> 6;

    float wreg[H][32];
#pragma unroll
    for (int h = 0; h < H; ++h)
#pragma unroll
        for (int k = 0; k < 32; ++k)
            wreg[h][k] = We[k * HC + h * 64 + lane];
    float attr[H], br[H];
#pragma unroll
    for (int h = 0; h < H; ++h) {
        attr[h] = att[h * 64 + lane];
        br[h] = bias[h * 64 + lane];
    }

    for (int n = wid; n < Nn; n += nw) {
        const int beg = row_ptr[n], end = row_ptr[n + 1];
        float xrh[H];
#pragma unroll
        for (int h = 0; h < H; ++h) xrh[h] = xr[(size_t)n * HC + h * 64 + lane];
        float mrun[H], den[H], acc[H];
#pragma unroll
        for (int h = 0; h < H; ++h) { mrun[h] = -1e30f; den[h] = 0.f; acc[h] = 0.f; }

        for (int i = beg - 1; i < end; ++i) {
            int s;
            const float4* eap;
            if (i < beg) {  // self loop
                s = n;
                eap = (const float4*)(ealoop + (size_t)n * 32);
            } else {
                int e = cidx[i];
                s = src[e];
                eap = (const float4*)(ea + (size_t)e * 32);
            }
            float4 ev[8];
#pragma unroll
            for (int q = 0; q < 8; ++q) ev[q] = eap[q];
            float xls[H];
#pragma unroll
            for (int h = 0; h < H; ++h) xls[h] = xl[(size_t)s * HC + h * 64 + lane];
            float al[H];
#pragma unroll
            for (int h = 0; h < H; ++h) {
                float ee = 0.f;
#pragma unroll
                for (int q = 0; q < 8; ++q) {
                    ee += ev[q].x * wreg[h][4 * q + 0];
                    ee += ev[q].y * wreg[h][4 * q + 1];
                    ee += ev[q].z * wreg[h][4 * q + 2];
                    ee += ev[q].w * wreg[h][4 * q + 3];
                }
                float m = xls[h] + xrh[h] + ee;
                m = m > 0.f ? m : 0.2f * m;
                al[h] = m * attr[h];
            }
            // wave-wide sum -> alpha per head (all lanes get the result)
#pragma unroll
            for (int off = 1; off < 64; off <<= 1) {
#pragma unroll
                for (int h = 0; h < H; ++h) al[h] += __shfl_xor(al[h], off);
            }
            // online softmax update
#pragma unroll
            for (int h = 0; h < H; ++h) {
                float nm = fmaxf(mrun[h], al[h]);
                float corr = __expf(mrun[h] - nm);
                float p = __expf(al[h] - nm);
                den[h] = den[h] * corr + p;
                acc[h] = acc[h] * corr + p * xls[h];
                mrun[h] = nm;
            }
        }
#pragma unroll
        for (int h = 0; h < H; ++h) {
            float r = acc[h] / den[h] + br[h];
            if (RELU) r = r > 0.f ? r : 0.01f * r;
            out[(size_t)n * HC + h * 64 + lane] = r;
        }
    }
}

// global_add_pool over sorted batch: block = 192 threads (one per channel),
// each block owns a contiguous node range, per-segment running sum, few atomics.
__global__ void k_pool(const float* __restrict__ h2, const int* __restrict__ batch,
                       int Nn, float* __restrict__ g) {
    const int c = threadIdx.x;  // 0..191
    const int n0 = blockIdx.x * 512;
    if (n0 >= Nn) return;
    const int n1 = (n0 + 512 < Nn) ? n0 + 512 : Nn;
    float s = 0.f;
    int cur = batch[n0];
    for (int n = n0; n < n1; ++n) {
        int b = batch[n];
        if (b != cur) {
            atomicAdd(&g[cur * 192 + c], s);
            s = 0.f;
            cur = b;
        }
        s += h2[(size_t)n * 192 + c];
    }
    atomicAdd(&g[cur * 192 + c], s);
}

__global__ void k_mlp(const float* __restrict__ g,
                      const float* W1, const float* c1, const float* W2, const float* c2,
                      const float* W3, const float* c3, const float* W4, const float* c4,
                      const float* W5, const float* c5, const float* W6, const float* c6,
                      float* __restrict__ out) {
    __shared__ float t0[8 * 192];
    __shared__ float t1[8 * 64];
    __shared__ float t2[8 * 32];
    __shared__ float t3[8 * 16];
    __shared__ float t4[8 * 8];
    const int tid = threadIdx.x;
    for (int i = tid; i < 8 * 192; i += 256) t0[i] = g[i];
    __syncthreads();
    for (int i = tid; i < 8 * 64; i += 256) {
        int r = i >> 6, c = i & 63;
        float s = c1[c];
        for (int k = 0; k < 192; ++k) s += t0[r * 192 + k] * W1[k * 64 + c];
        t1[i] = s > 0.f ? s : 0.01f * s;
    }
    __syncthreads();
    for (int i = tid; i < 8 * 32; i += 256) {
        int r = i >> 5, c = i & 31;
        float s = c2[c];
        for (int k = 0; k < 64; ++k) s += t1[r * 64 + k] * W2[k * 32 + c];
        t2[i] = s > 0.f ? s : 0.01f * s;
    }
    __syncthreads();
    for (int i = tid; i < 8 * 16; i += 256) {
        int r = i >> 4, c = i & 15;
        float s = c3[c];
        for (int k = 0; k < 32; ++k) s += t2[r * 32 + k] * W3[k * 16 + c];
        t3[i] = s > 0.f ? s : 0.01f * s;
    }
    __syncthreads();
    for (int i = tid; i < 8 * 8; i += 256) {
        int r = i >> 3, c = i & 7;
        float s = c4[c];
        for (int k = 0; k < 16; ++k) s += t3[r * 16 + k] * W4[k * 8 + c];
        t4[i] = s > 0.f ? s : 0.01f * s;
    }
    __syncthreads();
    if (tid < 8) {
        float s = c5[0];
        for (int k = 0; k < 8; ++k) s += t4[tid * 8 + k] * W5[k];
        s = s * W6[0] + c6[0];
        out[tid] = s;
    }
}

extern "C" void kernel_launch(void* const* d_in, const int* in_sizes, int n_in,
                              void* d_out, int out_size, void* d_ws, size_t ws_size,
                              hipStream_t stream) {
    const float* x     = (const float*)d_in[0];
    const int*   eidx  = (const int*)d_in[1];
    const float* ea    = (const float*)d_in[2];
    const int*   batch = (const int*)d_in[3];
    const float* Wl1 = (const float*)d_in[4];
    const float* bl1 = (const float*)d_in[5];
    const float* Wr1 = (const float*)d_in[6];
    const float* br1 = (const float*)d_in[7];
    const float* We1 = (const float*)d_in[8];
    const float* att1 = (const float*)d_in[9];
    const float* bias1 = (const float*)d_in[10];
    const float* Wl2 = (const float*)d_in[11];
    const float* bl2 = (const float*)d_in[12];
    const float* Wr2 = (const float*)d_in[13];
    const float* br2 = (const float*)d_in[14];
    const float* We2 = (const float*)d_in[15];
    const float* att2 = (const float*)d_in[16];
    const float* bias2 = (const float*)d_in[17];
    const float* W1 = (const float*)d_in[18];
    const float* c1 = (const float*)d_in[19];
    const float* W2 = (const float*)d_in[20];
    const float* c2 = (const float*)d_in[21];
    const float* W3 = (const float*)d_in[22];
    const float* c3 = (const float*)d_in[23];
    const float* W4 = (const float*)d_in[24];
    const float* c4 = (const float*)d_in[25];
    const float* W5 = (const float*)d_in[26];
    const float* c5 = (const float*)d_in[27];
    const float* W6 = (const float*)d_in[28];
    const float* c6 = (const float*)d_in[29];

    const int N = in_sizes[0] / 128;
    const int E = in_sizes[1] / 2;
    const int* srcs = eidx;
    const int* dsts = eidx + E;

    char* p = (char*)d_ws;
    auto alloc = [&](size_t bytes) -> char* {
        char* r = p;
        p += (bytes + 255) & ~(size_t)255;
        return r;
    };
    int*   deg     = (int*)alloc((size_t)N * 4);
    int*   row_ptr = (int*)alloc((size_t)(N + 1) * 4);
    int*   woff    = (int*)alloc((size_t)N * 4);
    int*   cidx    = (int*)alloc((size_t)E * 4);
    float* ealoop  = (float*)alloc((size_t)N * 32 * 4);
    float* xl      = (float*)alloc((size_t)N * 192 * 4);
    float* xr      = (float*)alloc((size_t)N * 192 * 4);
    float* h1      = (float*)alloc((size_t)N * 128 * 4);
    float* h2      = (float*)alloc((size_t)N * 192 * 4);
    float* gp      = (float*)alloc(8 * 192 * 4);

    hipMemsetAsync(deg, 0, (size_t)N * 4, stream);
    hipMemsetAsync(gp, 0, 8 * 192 * 4, stream);

    k_deg<<<(E + 255) / 256, 256, 0, stream>>>(dsts, E, deg);
    k_scan<<<1, 1024, 0, stream>>>(deg, N, row_ptr, woff);
    k_scatter<<<(E + 255) / 256, 256, 0, stream>>>(dsts, E, woff, cidx);
    k_ealoop<<<(N + 3) / 4, 256, 0, stream>>>(ea, cidx, row_ptr, N, ealoop);

    // conv1: H=2, HC=128
    k_xw<128><<<dim3(256, 4), 256, 0, stream>>>(x, N, Wl1, bl1, Wr1, br1, xl, xr);
    k_conv<2, true><<<1024, 256, 0, stream>>>(xl, xr, ealoop, ea, srcs, cidx, row_ptr,
                                              We1, att1, bias1, N, h1);
    // conv2: H=3, HC=192
    k_xw<192><<<dim3(256, 6), 256, 0, stream>>>(h1, N, Wl2, bl2, Wr2, br2, xl, xr);
    k_conv<3, true><<<1024, 256, 0, stream>>>(xl, xr, ealoop, ea, srcs, cidx, row_ptr,
                                              We2, att2, bias2, N, h2);

    k_pool<<<(N + 511) / 512, 192, 0, stream>>>(h2, batch, N, gp);
    k_mlp<<<1, 256, 0, stream>>>(gp, W1, c1, W2, c2, W3, c3, W4, c4, W5, c5, W6, c6,
                                 (float*)d_out);
}

// Round 2
// 5277.778 us; speedup vs baseline: 1.1668x; 1.1668x over previous
//
#include <hip/hip_runtime.h>
#include <hip/hip_bf16.h>
#include <math.h>

// ---------------------------------------------------------------------------
// GATv2 x2 + global_add_pool + MLP head, fp32.
// Conv = edge-parallel logits (+atomicMax dst-max) then light gather-CSR
// softmax-aggregate. CSR built with multi-block scan.
// ---------------------------------------------------------------------------

__device__ __forceinline__ unsigned enc_f(float f) {
    int b = __float_as_int(f);
    unsigned u = (unsigned)b;
    return (b >= 0) ? (u | 0x80000000u) : ~u;
}
__device__ __forceinline__ float dec_f(unsigned u) {
    int b = (u & 0x80000000u) ? (int)(u & 0x7fffffffu) : (int)~u;
    return __int_as_float(b);
}

__global__ void k_deg(const int* __restrict__ dst, int E, int* __restrict__ deg) {
    int e = blockIdx.x * blockDim.x + threadIdx.x;
    if (e < E) atomicAdd(&deg[dst[e]], 1);
}

// ---- multi-block exclusive scan: deg[N] -> row_ptr[N+1], woff[N] ----------
// scan1: 256 thr x 8 elem = 2048/block, writes per-elem inclusive + block sum
__global__ void k_scan1(const int* __restrict__ deg, int N,
                        int* __restrict__ incl, int* __restrict__ bsum) {
    __shared__ int ws4[4];
    const int tid = threadIdx.x;
    const int lane = tid & 63, w = tid >> 6;
    const int base = blockIdx.x * 2048;
    int v[8];
    int s = 0;
#pragma unroll
    for (int j = 0; j < 8; ++j) {
        int i = base + tid * 8 + j;
        v[j] = (i < N) ? deg[i] : 0;
        s += v[j];
    }
    int ps = s;
#pragma unroll
    for (int off = 1; off < 64; off <<= 1) {
        int t = __shfl_up(ps, off);
        if (lane >= off) ps += t;
    }
    if (lane == 63) ws4[w] = ps;
    __syncthreads();
    int woffs = 0;
#pragma unroll
    for (int k = 0; k < 4; ++k)
        if (k < w) woffs += ws4[k];
    int run = ps - s + woffs;  // exclusive prefix of this thread
#pragma unroll
    for (int j = 0; j < 8; ++j) {
        run += v[j];
        int i = base + tid * 8 + j;
        if (i < N) incl[i] = run;
    }
    if (tid == 255) bsum[blockIdx.x] = run;
}

__global__ void k_scan2(int* __restrict__ bsum, int nb) {
    if (threadIdx.x == 0) {
        int c = 0;
        for (int k = 0; k < nb; ++k) { int t = bsum[k]; bsum[k] = c; c += t; }
    }
}

__global__ void k_scan3(const int* __restrict__ incl, const int* __restrict__ deg,
                        const int* __restrict__ boff, int N,
                        int* __restrict__ row_ptr, int* __restrict__ woff) {
    int i = blockIdx.x * blockDim.x + threadIdx.x;
    if (i < N) {
        int v = incl[i] + boff[i >> 11];
        row_ptr[i + 1] = v;
        woff[i] = v - deg[i];
        if (i == 0) row_ptr[0] = 0;
    }
}

__global__ void k_scatter(const int* __restrict__ dst, int E,
                          int* __restrict__ woff, int* __restrict__ cidx) {
    int e = blockIdx.x * blockDim.x + threadIdx.x;
    if (e < E) { int p = atomicAdd(&woff[dst[e]], 1); cidx[p] = e; }
}

// edge-parallel sum of edge attrs into per-dst accumulator (mean done later)
__global__ void k_easum(const float* __restrict__ ea, const int* __restrict__ dst,
                        int E, float* __restrict__ easum) {
    int t = blockIdx.x * blockDim.x + threadIdx.x;
    int e = t >> 5, k = t & 31;
    if (e < E) atomicAdd(&easum[(size_t)dst[e] * 32 + k], ea[(size_t)e * 32 + k]);
}

// out[n][col] = in[n][0:128] . W[:,col] + b[col], W column held in 128 VGPRs.
template <int HC>
__global__ void k_xw(const float* __restrict__ in, int N,
                     const float* __restrict__ Wl, const float* __restrict__ bl,
                     const float* __restrict__ Wr, const float* __restrict__ br,
                     float* __restrict__ outl, float* __restrict__ outr) {
    constexpr int NCH = HC / 64;
    int chunk = blockIdx.y;
    const float* W;
    const float* b;
    float* out;
    int cc;
    if (chunk < NCH) { W = Wl; b = bl; out = outl; cc = chunk; }
    else             { W = Wr; b = br; out = outr; cc = chunk - NCH; }
    const int lane = threadIdx.x & 63;
    const int col = cc * 64 + lane;
    float wreg[128];
#pragma unroll
    for (int k = 0; k < 128; ++k) wreg[k] = W[k * HC + col];
    const float breg = b[col];
    const int wid = (blockIdx.x * blockDim.x + threadIdx.x) >> 6;
    const int nw = (gridDim.x * blockDim.x) >> 6;
    for (int n = wid; n < N; n += nw) {
        const float4* xp = (const float4*)(in + (size_t)n * 128);
        float a0 = 0.f, a1 = 0.f, a2 = 0.f, a3 = 0.f;
#pragma unroll
        for (int q = 0; q < 32; ++q) {
            float4 v = xp[q];
            a0 += v.x * wreg[4 * q + 0];
            a1 += v.y * wreg[4 * q + 1];
            a2 += v.z * wreg[4 * q + 2];
            a3 += v.w * wreg[4 * q + 3];
        }
        out[(size_t)n * HC + col] = (a0 + a1) + (a2 + a3) + breg;
    }
}

// self-loop logits: one wave per node; ea_loop = easum/deg fused here
template <int H>
__global__ void k_selfalpha(const float* __restrict__ xl, const float* __restrict__ xr,
                            const float* __restrict__ easum, const int* __restrict__ deg,
                            const float* __restrict__ We, const float* __restrict__ att,
                            int Nn, float* __restrict__ aself, unsigned* __restrict__ amax) {
    constexpr int HC = H * 64;
    const int lane = threadIdx.x & 63;
    const int n = (blockIdx.x * blockDim.x + threadIdx.x) >> 6;
    if (n >= Nn) return;
    float wreg[H][32], attr[H];
#pragma unroll
    for (int h = 0; h < H; ++h) {
#pragma unroll
        for (int k = 0; k < 32; ++k) wreg[h][k] = We[k * HC + h * 64 + lane];
        attr[h] = att[h * 64 + lane];
    }
    int dg = deg[n];
    float inv = 1.f / (float)(dg > 0 ? dg : 1);
    const float4* ep = (const float4*)(easum + (size_t)n * 32);
    float4 ev[8];
#pragma unroll
    for (int q = 0; q < 8; ++q) ev[q] = ep[q];
    float al[H];
#pragma unroll
    for (int h = 0; h < H; ++h) {
        float ee = 0.f;
#pragma unroll
        for (int q = 0; q < 8; ++q) {
            ee += ev[q].x * wreg[h][4 * q + 0];
            ee += ev[q].y * wreg[h][4 * q + 1];
            ee += ev[q].z * wreg[h][4 * q + 2];
            ee += ev[q].w * wreg[h][4 * q + 3];
        }
        float m = xl[(size_t)n * HC + h * 64 + lane] + xr[(size_t)n * HC + h * 64 + lane]
                + ee * inv;
        m = m > 0.f ? m : 0.2f * m;
        al[h] = m * attr[h];
    }
#pragma unroll
    for (int off = 1; off < 64; off <<= 1)
#pragma unroll
        for (int h = 0; h < H; ++h) al[h] += __shfl_xor(al[h], off);
    if (lane == 0) {
#pragma unroll
        for (int h = 0; h < H; ++h) {
            aself[(size_t)n * H + h] = al[h];
            atomicMax(&amax[(size_t)n * H + h], enc_f(al[h]));
        }
    }
}

// edge-parallel logits: one wave handles EPW consecutive edges
template <int H>
__global__ void k_alpha(const float* __restrict__ xl, const float* __restrict__ xr,
                        const float* __restrict__ ea,
                        const int* __restrict__ src, const int* __restrict__ dst, int E,
                        const float* __restrict__ We, const float* __restrict__ att,
                        float* __restrict__ alpha, unsigned* __restrict__ amax) {
    constexpr int HC = H * 64;
    constexpr int EPW = 8;
    const int lane = threadIdx.x & 63;
    const int wid = (blockIdx.x * blockDim.x + threadIdx.x) >> 6;
    float wreg[H][32], attr[H];
#pragma unroll
    for (int h = 0; h < H; ++h) {
#pragma unroll
        for (int k = 0; k < 32; ++k) wreg[h][k] = We[k * HC + h * 64 + lane];
        attr[h] = att[h * 64 + lane];
    }
    const int e0 = wid * EPW;
    const int e1 = (e0 + EPW < E) ? e0 + EPW : E;
    for (int e = e0; e < e1; ++e) {
        int s = src[e], d = dst[e];
        const float4* ep = (const float4*)(ea + (size_t)e * 32);
        float4 ev[8];
#pragma unroll
        for (int q = 0; q < 8; ++q) ev[q] = ep[q];
        float al[H];
#pragma unroll
        for (int h = 0; h < H; ++h) {
            float ee = 0.f;
#pragma unroll
            for (int q = 0; q < 8; ++q) {
                ee += ev[q].x * wreg[h][4 * q + 0];
                ee += ev[q].y * wreg[h][4 * q + 1];
                ee += ev[q].z * wreg[h][4 * q + 2];
                ee += ev[q].w * wreg[h][4 * q + 3];
            }
            float m = xl[(size_t)s * HC + h * 64 + lane]
                    + xr[(size_t)d * HC + h * 64 + lane] + ee;
            m = m > 0.f ? m : 0.2f * m;
            al[h] = m * attr[h];
        }
#pragma unroll
        for (int off = 1; off < 64; off <<= 1)
#pragma unroll
            for (int h = 0; h < H; ++h) al[h] += __shfl_xor(al[h], off);
        if (lane == 0) {
#pragma unroll
            for (int h = 0; h < H; ++h) {
                alpha[(size_t)e * H + h] = al[h];
                atomicMax(&amax[(size_t)d * H + h], enc_f(al[h]));
            }
        }
    }
}

// gather-CSR softmax aggregate: one wave per node, lane = channel
template <int H, bool RELU>
__global__ void k_aggr(const float* __restrict__ xl,
                       const int* __restrict__ src, const int* __restrict__ cidx,
                       const int* __restrict__ row_ptr,
                       const float* __restrict__ alpha, const float* __restrict__ aself,
                       const unsigned* __restrict__ amax,
                       const float* __restrict__ bias, int Nn,
                       float* __restrict__ out) {
    constexpr int HC = H * 64;
    const int lane = threadIdx.x & 63;
    const int n = (blockIdx.x * blockDim.x + threadIdx.x) >> 6;
    if (n >= Nn) return;
    float mx[H], den[H], acc[H];
#pragma unroll
    for (int h = 0; h < H; ++h) {
        mx[h] = dec_f(amax[(size_t)n * H + h]);
        float p = __expf(aself[(size_t)n * H + h] - mx[h]);
        den[h] = p;
        acc[h] = p * xl[(size_t)n * HC + h * 64 + lane];
    }
    const int beg = row_ptr[n], end = row_ptr[n + 1];
    int i = beg;
    for (; i + 1 < end; i += 2) {
        int ea0 = cidx[i], ea1 = cidx[i + 1];
        int s0 = src[ea0], s1 = src[ea1];
        float xv0[H], xv1[H], p0[H], p1[H];
#pragma unroll
        for (int h = 0; h < H; ++h) {
            xv0[h] = xl[(size_t)s0 * HC + h * 64 + lane];
            xv1[h] = xl[(size_t)s1 * HC + h * 64 + lane];
            p0[h] = __expf(alpha[(size_t)ea0 * H + h] - mx[h]);
            p1[h] = __expf(alpha[(size_t)ea1 * H + h] - mx[h]);
        }
#pragma unroll
        for (int h = 0; h < H; ++h) {
            den[h] += p0[h] + p1[h];
            acc[h] += p0[h] * xv0[h] + p1[h] * xv1[h];
        }
    }
    if (i < end) {
        int e = cidx[i];
        int s = src[e];
#pragma unroll
        for (int h = 0; h < H; ++h) {
            float p = __expf(alpha[(size_t)e * H + h] - mx[h]);
            den[h] += p;
            acc[h] += p * xl[(size_t)s * HC + h * 64 + lane];
        }
    }
#pragma unroll
    for (int h = 0; h < H; ++h) {
        float r = acc[h] / den[h] + bias[h * 64 + lane];
        if (RELU) r = r > 0.f ? r : 0.01f * r;
        out[(size_t)n * HC + h * 64 + lane] = r;
    }
}

// global_add_pool over sorted batch
__global__ void k_pool(const float* __restrict__ h2, const int* __restrict__ batch,
                       int Nn, float* __restrict__ g) {
    const int c = threadIdx.x;  // 0..191
    const int n0 = blockIdx.x * 128;
    if (n0 >= Nn) return;
    const int n1 = (n0 + 128 < Nn) ? n0 + 128 : Nn;
    float s = 0.f;
    int cur = batch[n0];
    for (int n = n0; n < n1; ++n) {
        int b = batch[n];
        if (b != cur) {
            atomicAdd(&g[cur * 192 + c], s);
            s = 0.f;
            cur = b;
        }
        s += h2[(size_t)n * 192 + c];
    }
    atomicAdd(&g[cur * 192 + c], s);
}

__global__ void k_mlp(const float* __restrict__ g,
                      const float* W1, const float* c1, const float* W2, const float* c2,
                      const float* W3, const float* c3, const float* W4, const float* c4,
                      const float* W5, const float* c5, const float* W6, const float* c6,
                      float* __restrict__ out) {
    __shared__ float t0[8 * 192];
    __shared__ float t1[8 * 64];
    __shared__ float t2[8 * 32];
    __shared__ float t3[8 * 16];
    __shared__ float t4[8 * 8];
    const int tid = threadIdx.x;
    for (int i = tid; i < 8 * 192; i += 256) t0[i] = g[i];
    __syncthreads();
    for (int i = tid; i < 8 * 64; i += 256) {
        int r = i >> 6, c = i & 63;
        float s = c1[c];
        for (int k = 0; k < 192; ++k) s += t0[r * 192 + k] * W1[k * 64 + c];
        t1[i] = s > 0.f ? s : 0.01f * s;
    }
    __syncthreads();
    for (int i = tid; i < 8 * 32; i += 256) {
        int r = i >> 5, c = i & 31;
        float s = c2[c];
        for (int k = 0; k < 64; ++k) s += t1[r * 64 + k] * W2[k * 32 + c];
        t2[i] = s > 0.f ? s : 0.01f * s;
    }
    __syncthreads();
    for (int i = tid; i < 8 * 16; i += 256) {
        int r = i >> 4, c = i & 15;
        float s = c3[c];
        for (int k = 0; k < 32; ++k) s += t2[r * 32 + k] * W3[k * 16 + c];
        t3[i] = s > 0.f ? s : 0.01f * s;
    }
    __syncthreads();
    for (int i = tid; i < 8 * 8; i += 256) {
        int r = i >> 3, c = i & 7;
        float s = c4[c];
        for (int k = 0; k < 16; ++k) s += t3[r * 16 + k] * W4[k * 8 + c];
        t4[i] = s > 0.f ? s : 0.01f * s;
    }
    __syncthreads();
    if (tid < 8) {
        float s = c5[0];
        for (int k = 0; k < 8; ++k) s += t4[tid * 8 + k] * W5[k];
        s = s * W6[0] + c6[0];
        out[tid] = s;
    }
}

extern "C" void kernel_launch(void* const* d_in, const int* in_sizes, int n_in,
                              void* d_out, int out_size, void* d_ws, size_t ws_size,
                              hipStream_t stream) {
    const float* x     = (const float*)d_in[0];
    const int*   eidx  = (const int*)d_in[1];
    const float* ea    = (const float*)d_in[2];
    const int*   batch = (const int*)d_in[3];
    const float* Wl1 = (const float*)d_in[4];
    const float* bl1 = (const float*)d_in[5];
    const float* Wr1 = (const float*)d_in[6];
    const float* br1 = (const float*)d_in[7];
    const float* We1 = (const float*)d_in[8];
    const float* att1 = (const float*)d_in[9];
    const float* bias1 = (const float*)d_in[10];
    const float* Wl2 = (const float*)d_in[11];
    const float* bl2 = (const float*)d_in[12];
    const float* Wr2 = (const float*)d_in[13];
    const float* br2 = (const float*)d_in[14];
    const float* We2 = (const float*)d_in[15];
    const float* att2 = (const float*)d_in[16];
    const float* bias2 = (const float*)d_in[17];
    const float* W1 = (const float*)d_in[18];
    const float* c1 = (const float*)d_in[19];
    const float* W2 = (const float*)d_in[20];
    const float* c2 = (const float*)d_in[21];
    const float* W3 = (const float*)d_in[22];
    const float* c3 = (const float*)d_in[23];
    const float* W4 = (const float*)d_in[24];
    const float* c4 = (const float*)d_in[25];
    const float* W5 = (const float*)d_in[26];
    const float* c5 = (const float*)d_in[27];
    const float* W6 = (const float*)d_in[28];
    const float* c6 = (const float*)d_in[29];

    const int N = in_sizes[0] / 128;
    const int E = in_sizes[1] / 2;
    const int* srcs = eidx;
    const int* dsts = eidx + E;

    char* p = (char*)d_ws;
    auto alloc = [&](size_t bytes) -> char* {
        char* r = p;
        p += (bytes + 255) & ~(size_t)255;
        return r;
    };
    int*      deg     = (int*)alloc((size_t)N * 4);
    int*      row_ptr = (int*)alloc((size_t)(N + 1) * 4);
    int*      woff    = (int*)alloc((size_t)N * 4);
    int*      cidx    = (int*)alloc((size_t)E * 4);
    int*      incl    = (int*)alloc((size_t)N * 4);
    int*      bsum    = (int*)alloc(64 * 4);
    float*    easum   = (float*)alloc((size_t)N * 32 * 4);
    float*    xl      = (float*)alloc((size_t)N * 192 * 4);
    float*    xr      = (float*)alloc((size_t)N * 192 * 4);
    float*    h1      = (float*)alloc((size_t)N * 128 * 4);
    float*    h2      = (float*)alloc((size_t)N * 192 * 4);
    float*    alpha   = (float*)alloc((size_t)E * 3 * 4);
    float*    aself   = (float*)alloc((size_t)N * 3 * 4);
    unsigned* amax1   = (unsigned*)alloc((size_t)N * 2 * 4);
    unsigned* amax2   = (unsigned*)alloc((size_t)N * 3 * 4);
    float*    gp      = (float*)alloc(8 * 192 * 4);

    hipMemsetAsync(deg, 0, (size_t)N * 4, stream);
    hipMemsetAsync(easum, 0, (size_t)N * 32 * 4, stream);
    hipMemsetAsync(amax1, 0, (size_t)N * 2 * 4, stream);
    hipMemsetAsync(amax2, 0, (size_t)N * 3 * 4, stream);
    hipMemsetAsync(gp, 0, 8 * 192 * 4, stream);

    // CSR build
    const int nb = (N + 2047) / 2048;
    k_deg<<<(E + 255) / 256, 256, 0, stream>>>(dsts, E, deg);
    k_scan1<<<nb, 256, 0, stream>>>(deg, N, incl, bsum);
    k_scan2<<<1, 64, 0, stream>>>(bsum, nb);
    k_scan3<<<(N + 255) / 256, 256, 0, stream>>>(incl, deg, bsum, N, row_ptr, woff);
    k_scatter<<<(E + 255) / 256, 256, 0, stream>>>(dsts, E, woff, cidx);
    k_easum<<<((E * 32) + 255) / 256, 256, 0, stream>>>(ea, dsts, E, easum);

    const int ablk = ((E + 7) / 8 + 3) / 4;   // k_alpha blocks (4 waves, 8 edges/wave)
    const int nblk = (N + 3) / 4;             // node-parallel blocks (4 waves)

    // conv1: H=2, HC=128
    k_xw<128><<<dim3(256, 4), 256, 0, stream>>>(x, N, Wl1, bl1, Wr1, br1, xl, xr);
    k_selfalpha<2><<<nblk, 256, 0, stream>>>(xl, xr, easum, deg, We1, att1, N, aself, amax1);
    k_alpha<2><<<ablk, 256, 0, stream>>>(xl, xr, ea, srcs, dsts, E, We1, att1, alpha, amax1);
    k_aggr<2, true><<<nblk, 256, 0, stream>>>(xl, srcs, cidx, row_ptr, alpha, aself, amax1,
                                              bias1, N, h1);
    // conv2: H=3, HC=192
    k_xw<192><<<dim3(256, 6), 256, 0, stream>>>(h1, N, Wl2, bl2, Wr2, br2, xl, xr);
    k_selfalpha<3><<<nblk, 256, 0, stream>>>(xl, xr, easum, deg, We2, att2, N, aself, amax2);
    k_alpha<3><<<ablk, 256, 0, stream>>>(xl, xr, ea, srcs, dsts, E, We2, att2, alpha, amax2);
    k_aggr<3, true><<<nblk, 256, 0, stream>>>(xl, srcs, cidx, row_ptr, alpha, aself, amax2,
                                              bias2, N, h2);

    k_pool<<<(N + 127) / 128, 192, 0, stream>>>(h2, batch, N, gp);
    k_mlp<<<1, 256, 0, stream>>>(gp, W1, c1, W2, c2, W3, c3, W4, c4, W5, c5, W6, c6,
                                 (float*)d_out);
}

// Round 3
// 1780.290 us; speedup vs baseline: 3.4591x; 2.9646x over previous
//
#include <hip/hip_runtime.h>
#include <hip/hip_bf16.h>
#include <math.h>

// ---------------------------------------------------------------------------
// GATv2 x2 + global_add_pool + MLP head, fp32.
// k_xw: LDS-tiled GEMM (spill-proof). Conv: edge-parallel logits + gather-CSR
// softmax aggregate, __launch_bounds__ to keep We in registers.
// ---------------------------------------------------------------------------

__device__ __forceinline__ unsigned enc_f(float f) {
    int b = __float_as_int(f);
    unsigned u = (unsigned)b;
    return (b >= 0) ? (u | 0x80000000u) : ~u;
}
__device__ __forceinline__ float dec_f(unsigned u) {
    int b = (u & 0x80000000u) ? (int)(u & 0x7fffffffu) : (int)~u;
    return __int_as_float(b);
}

__global__ void k_deg(const int* __restrict__ dst, int E, int* __restrict__ deg) {
    int e = blockIdx.x * blockDim.x + threadIdx.x;
    if (e < E) atomicAdd(&deg[dst[e]], 1);
}

// ---- multi-block exclusive scan: deg[N] -> row_ptr[N+1], woff[N] ----------
__global__ void k_scan1(const int* __restrict__ deg, int N,
                        int* __restrict__ incl, int* __restrict__ bsum) {
    __shared__ int ws4[4];
    const int tid = threadIdx.x;
    const int lane = tid & 63, w = tid >> 6;
    const int base = blockIdx.x * 2048;
    int v[8];
    int s = 0;
#pragma unroll
    for (int j = 0; j < 8; ++j) {
        int i = base + tid * 8 + j;
        v[j] = (i < N) ? deg[i] : 0;
        s += v[j];
    }
    int ps = s;
#pragma unroll
    for (int off = 1; off < 64; off <<= 1) {
        int t = __shfl_up(ps, off);
        if (lane >= off) ps += t;
    }
    if (lane == 63) ws4[w] = ps;
    __syncthreads();
    int woffs = 0;
#pragma unroll
    for (int k = 0; k < 4; ++k)
        if (k < w) woffs += ws4[k];
    int run = ps - s + woffs;
#pragma unroll
    for (int j = 0; j < 8; ++j) {
        run += v[j];
        int i = base + tid * 8 + j;
        if (i < N) incl[i] = run;
    }
    if (tid == 255) bsum[blockIdx.x] = run;
}

__global__ void k_scan2(int* __restrict__ bsum, int nb) {
    if (threadIdx.x == 0) {
        int c = 0;
        for (int k = 0; k < nb; ++k) { int t = bsum[k]; bsum[k] = c; c += t; }
    }
}

__global__ void k_scan3(const int* __restrict__ incl, const int* __restrict__ deg,
                        const int* __restrict__ boff, int N,
                        int* __restrict__ row_ptr, int* __restrict__ woff) {
    int i = blockIdx.x * blockDim.x + threadIdx.x;
    if (i < N) {
        int v = incl[i] + boff[i >> 11];
        row_ptr[i + 1] = v;
        woff[i] = v - deg[i];
        if (i == 0) row_ptr[0] = 0;
    }
}

__global__ void k_scatter(const int* __restrict__ dst, int E,
                          int* __restrict__ woff, int* __restrict__ cidx) {
    int e = blockIdx.x * blockDim.x + threadIdx.x;
    if (e < E) { int p = atomicAdd(&woff[dst[e]], 1); cidx[p] = e; }
}

__global__ void k_easum(const float* __restrict__ ea, const int* __restrict__ dst,
                        int E, float* __restrict__ easum) {
    int t = blockIdx.x * blockDim.x + threadIdx.x;
    int e = t >> 5, k = t & 31;
    if (e < E) atomicAdd(&easum[(size_t)dst[e] * 32 + k], ea[(size_t)e * 32 + k]);
}

// ---- LDS-tiled GEMM: out{l,r}[n][col] = in[n][:128] . W{l,r}[:, col] + b ----
// 64-node x 64-col tile, full K=128. Xs transposed [k][row] so fragments are
// contiguous (ds_read_b128). Each thread: 4x4 micro-tile. ~40 VGPR, no spill.
template <int HC>
__global__ __launch_bounds__(256, 2) void k_xw(
        const float* __restrict__ in, int N,
        const float* __restrict__ Wl, const float* __restrict__ bl,
        const float* __restrict__ Wr, const float* __restrict__ br,
        float* __restrict__ outl, float* __restrict__ outr) {
    __shared__ float Xs[128][68];  // [k][row], +4 pad, 34.0 KB
    __shared__ float Ws[128][64];  // [k][col], 32 KB
    const int tid = threadIdx.x;
    const int m0 = blockIdx.x * 64;
    const int cc = blockIdx.y;  // 64-col chunk

    // stage X transposed (coalesced float4 global reads)
#pragma unroll
    for (int t = 0; t < 8; ++t) {
        int idx4 = tid + t * 256;
        int r = idx4 >> 5, k4 = idx4 & 31;
        int n = m0 + r;
        float4 v = make_float4(0.f, 0.f, 0.f, 0.f);
        if (n < N) v = ((const float4*)in)[(size_t)n * 32 + k4];
        Xs[k4 * 4 + 0][r] = v.x;
        Xs[k4 * 4 + 1][r] = v.y;
        Xs[k4 * 4 + 2][r] = v.z;
        Xs[k4 * 4 + 3][r] = v.w;
    }

    const int rm = tid >> 4, rn = tid & 15;
    float acc[4][4];

#pragma unroll
    for (int mat = 0; mat < 2; ++mat) {
        const float* W = mat ? Wr : Wl;
        const float* b = mat ? br : bl;
        float* out = mat ? outr : outl;
        __syncthreads();  // iter0: nothing pending; iter1: prev compute done
#pragma unroll
        for (int i = tid; i < 128 * 64; i += 256) {
            int k = i >> 6, c = i & 63;
            Ws[k][c] = W[(size_t)k * HC + cc * 64 + c];
        }
        __syncthreads();  // X + W staged
#pragma unroll
        for (int i = 0; i < 4; ++i)
#pragma unroll
            for (int j = 0; j < 4; ++j) acc[i][j] = 0.f;
#pragma unroll 8
        for (int k = 0; k < 128; ++k) {
            float4 a = *(const float4*)&Xs[k][rm * 4];
            float4 bv = *(const float4*)&Ws[k][rn * 4];
            acc[0][0] += a.x * bv.x; acc[0][1] += a.x * bv.y;
            acc[0][2] += a.x * bv.z; acc[0][3] += a.x * bv.w;
            acc[1][0] += a.y * bv.x; acc[1][1] += a.y * bv.y;
            acc[1][2] += a.y * bv.z; acc[1][3] += a.y * bv.w;
            acc[2][0] += a.z * bv.x; acc[2][1] += a.z * bv.y;
            acc[2][2] += a.z * bv.z; acc[2][3] += a.z * bv.w;
            acc[3][0] += a.w * bv.x; acc[3][1] += a.w * bv.y;
            acc[3][2] += a.w * bv.z; acc[3][3] += a.w * bv.w;
        }
        float4 bb = *(const float4*)&b[cc * 64 + rn * 4];
#pragma unroll
        for (int i = 0; i < 4; ++i) {
            int n = m0 + rm * 4 + i;
            if (n < N) {
                float4 o = make_float4(acc[i][0] + bb.x, acc[i][1] + bb.y,
                                       acc[i][2] + bb.z, acc[i][3] + bb.w);
                *(float4*)&out[(size_t)n * HC + cc * 64 + rn * 4] = o;
            }
        }
    }
}

// self-loop logits: one wave per node; ea_loop = easum/deg fused here
template <int H>
__global__ __launch_bounds__(256, 2) void k_selfalpha(
        const float* __restrict__ xl, const float* __restrict__ xr,
        const float* __restrict__ easum, const int* __restrict__ deg,
        const float* __restrict__ We, const float* __restrict__ att,
        int Nn, float* __restrict__ aself, unsigned* __restrict__ amax) {
    constexpr int HC = H * 64;
    const int lane = threadIdx.x & 63;
    const int n = (blockIdx.x * blockDim.x + threadIdx.x) >> 6;
    if (n >= Nn) return;
    float wreg[H][32], attr[H];
#pragma unroll
    for (int h = 0; h < H; ++h) {
#pragma unroll
        for (int k = 0; k < 32; ++k) wreg[h][k] = We[k * HC + h * 64 + lane];
        attr[h] = att[h * 64 + lane];
    }
    int dg = deg[n];
    float inv = 1.f / (float)(dg > 0 ? dg : 1);
    const float4* ep = (const float4*)(easum + (size_t)n * 32);
    float4 ev[8];
#pragma unroll
    for (int q = 0; q < 8; ++q) ev[q] = ep[q];
    float al[H];
#pragma unroll
    for (int h = 0; h < H; ++h) {
        float ee = 0.f;
#pragma unroll
        for (int q = 0; q < 8; ++q) {
            ee += ev[q].x * wreg[h][4 * q + 0];
            ee += ev[q].y * wreg[h][4 * q + 1];
            ee += ev[q].z * wreg[h][4 * q + 2];
            ee += ev[q].w * wreg[h][4 * q + 3];
        }
        float m = xl[(size_t)n * HC + h * 64 + lane] + xr[(size_t)n * HC + h * 64 + lane]
                + ee * inv;
        m = m > 0.f ? m : 0.2f * m;
        al[h] = m * attr[h];
    }
#pragma unroll
    for (int off = 1; off < 64; off <<= 1)
#pragma unroll
        for (int h = 0; h < H; ++h) al[h] += __shfl_xor(al[h], off);
    if (lane == 0) {
#pragma unroll
        for (int h = 0; h < H; ++h) {
            aself[(size_t)n * H + h] = al[h];
            atomicMax(&amax[(size_t)n * H + h], enc_f(al[h]));
        }
    }
}

// edge-parallel logits: one wave handles EPW consecutive edges
template <int H>
__global__ __launch_bounds__(256, 2) void k_alpha(
        const float* __restrict__ xl, const float* __restrict__ xr,
        const float* __restrict__ ea,
        const int* __restrict__ src, const int* __restrict__ dst, int E,
        const float* __restrict__ We, const float* __restrict__ att,
        float* __restrict__ alpha, unsigned* __restrict__ amax) {
    constexpr int HC = H * 64;
    constexpr int EPW = 8;
    const int lane = threadIdx.x & 63;
    const int wid = (blockIdx.x * blockDim.x + threadIdx.x) >> 6;
    float wreg[H][32], attr[H];
#pragma unroll
    for (int h = 0; h < H; ++h) {
#pragma unroll
        for (int k = 0; k < 32; ++k) wreg[h][k] = We[k * HC + h * 64 + lane];
        attr[h] = att[h * 64 + lane];
    }
    const int e0 = wid * EPW;
    const int e1 = (e0 + EPW < E) ? e0 + EPW : E;
    for (int e = e0; e < e1; ++e) {
        int s = src[e], d = dst[e];
        const float4* ep = (const float4*)(ea + (size_t)e * 32);
        float4 ev[8];
#pragma unroll
        for (int q = 0; q < 8; ++q) ev[q] = ep[q];
        float al[H];
#pragma unroll
        for (int h = 0; h < H; ++h) {
            float ee = 0.f;
#pragma unroll
            for (int q = 0; q < 8; ++q) {
                ee += ev[q].x * wreg[h][4 * q + 0];
                ee += ev[q].y * wreg[h][4 * q + 1];
                ee += ev[q].z * wreg[h][4 * q + 2];
                ee += ev[q].w * wreg[h][4 * q + 3];
            }
            float m = xl[(size_t)s * HC + h * 64 + lane]
                    + xr[(size_t)d * HC + h * 64 + lane] + ee;
            m = m > 0.f ? m : 0.2f * m;
            al[h] = m * attr[h];
        }
#pragma unroll
        for (int off = 1; off < 64; off <<= 1)
#pragma unroll
            for (int h = 0; h < H; ++h) al[h] += __shfl_xor(al[h], off);
        if (lane == 0) {
#pragma unroll
            for (int h = 0; h < H; ++h) {
                alpha[(size_t)e * H + h] = al[h];
                atomicMax(&amax[(size_t)d * H + h], enc_f(al[h]));
            }
        }
    }
}

// gather-CSR softmax aggregate: one wave per node, lane = channel
template <int H, bool RELU>
__global__ __launch_bounds__(256, 2) void k_aggr(
        const float* __restrict__ xl,
        const int* __restrict__ src, const int* __restrict__ cidx,
        const int* __restrict__ row_ptr,
        const float* __restrict__ alpha, const float* __restrict__ aself,
        const unsigned* __restrict__ amax,
        const float* __restrict__ bias, int Nn,
        float* __restrict__ out) {
    constexpr int HC = H * 64;
    const int lane = threadIdx.x & 63;
    const int n = (blockIdx.x * blockDim.x + threadIdx.x) >> 6;
    if (n >= Nn) return;
    float mx[H], den[H], acc[H];
#pragma unroll
    for (int h = 0; h < H; ++h) {
        mx[h] = dec_f(amax[(size_t)n * H + h]);
        float p = __expf(aself[(size_t)n * H + h] - mx[h]);
        den[h] = p;
        acc[h] = p * xl[(size_t)n * HC + h * 64 + lane];
    }
    const int beg = row_ptr[n], end = row_ptr[n + 1];
    int i = beg;
    for (; i + 1 < end; i += 2) {
        int ea0 = cidx[i], ea1 = cidx[i + 1];
        int s0 = src[ea0], s1 = src[ea1];
        float xv0[H], xv1[H], p0[H], p1[H];
#pragma unroll
        for (int h = 0; h < H; ++h) {
            xv0[h] = xl[(size_t)s0 * HC + h * 64 + lane];
            xv1[h] = xl[(size_t)s1 * HC + h * 64 + lane];
            p0[h] = __expf(alpha[(size_t)ea0 * H + h] - mx[h]);
            p1[h] = __expf(alpha[(size_t)ea1 * H + h] - mx[h]);
        }
#pragma unroll
        for (int h = 0; h < H; ++h) {
            den[h] += p0[h] + p1[h];
            acc[h] += p0[h] * xv0[h] + p1[h] * xv1[h];
        }
    }
    if (i < end) {
        int e = cidx[i];
        int s = src[e];
#pragma unroll
        for (int h = 0; h < H; ++h) {
            float p = __expf(alpha[(size_t)e * H + h] - mx[h]);
            den[h] += p;
            acc[h] += p * xl[(size_t)s * HC + h * 64 + lane];
        }
    }
#pragma unroll
    for (int h = 0; h < H; ++h) {
        float r = acc[h] / den[h] + bias[h * 64 + lane];
        if (RELU) r = r > 0.f ? r : 0.01f * r;
        out[(size_t)n * HC + h * 64 + lane] = r;
    }
}

// global_add_pool over sorted batch
__global__ void k_pool(const float* __restrict__ h2, const int* __restrict__ batch,
                       int Nn, float* __restrict__ g) {
    const int c = threadIdx.x;  // 0..191
    const int n0 = blockIdx.x * 128;
    if (n0 >= Nn) return;
    const int n1 = (n0 + 128 < Nn) ? n0 + 128 : Nn;
    float s = 0.f;
    int cur = batch[n0];
    for (int n = n0; n < n1; ++n) {
        int b = batch[n];
        if (b != cur) {
            atomicAdd(&g[cur * 192 + c], s);
            s = 0.f;
            cur = b;
        }
        s += h2[(size_t)n * 192 + c];
    }
    atomicAdd(&g[cur * 192 + c], s);
}

__global__ void k_mlp(const float* __restrict__ g,
                      const float* W1, const float* c1, const float* W2, const float* c2,
                      const float* W3, const float* c3, const float* W4, const float* c4,
                      const float* W5, const float* c5, const float* W6, const float* c6,
                      float* __restrict__ out) {
    __shared__ float t0[8 * 192];
    __shared__ float t1[8 * 64];
    __shared__ float t2[8 * 32];
    __shared__ float t3[8 * 16];
    __shared__ float t4[8 * 8];
    const int tid = threadIdx.x;
    for (int i = tid; i < 8 * 192; i += 256) t0[i] = g[i];
    __syncthreads();
    for (int i = tid; i < 8 * 64; i += 256) {
        int r = i >> 6, c = i & 63;
        float s = c1[c];
        for (int k = 0; k < 192; ++k) s += t0[r * 192 + k] * W1[k * 64 + c];
        t1[i] = s > 0.f ? s : 0.01f * s;
    }
    __syncthreads();
    for (int i = tid; i < 8 * 32; i += 256) {
        int r = i >> 5, c = i & 31;
        float s = c2[c];
        for (int k = 0; k < 64; ++k) s += t1[r * 64 + k] * W2[k * 32 + c];
        t2[i] = s > 0.f ? s : 0.01f * s;
    }
    __syncthreads();
    for (int i = tid; i < 8 * 16; i += 256) {
        int r = i >> 4, c = i & 15;
        float s = c3[c];
        for (int k = 0; k < 32; ++k) s += t2[r * 32 + k] * W3[k * 16 + c];
        t3[i] = s > 0.f ? s : 0.01f * s;
    }
    __syncthreads();
    for (int i = tid; i < 8 * 8; i += 256) {
        int r = i >> 3, c = i & 7;
        float s = c4[c];
        for (int k = 0; k < 16; ++k) s += t3[r * 16 + k] * W4[k * 8 + c];
        t4[i] = s > 0.f ? s : 0.01f * s;
    }
    __syncthreads();
    if (tid < 8) {
        float s = c5[0];
        for (int k = 0; k < 8; ++k) s += t4[tid * 8 + k] * W5[k];
        s = s * W6[0] + c6[0];
        out[tid] = s;
    }
}

extern "C" void kernel_launch(void* const* d_in, const int* in_sizes, int n_in,
                              void* d_out, int out_size, void* d_ws, size_t ws_size,
                              hipStream_t stream) {
    const float* x     = (const float*)d_in[0];
    const int*   eidx  = (const int*)d_in[1];
    const float* ea    = (const float*)d_in[2];
    const int*   batch = (const int*)d_in[3];
    const float* Wl1 = (const float*)d_in[4];
    const float* bl1 = (const float*)d_in[5];
    const float* Wr1 = (const float*)d_in[6];
    const float* br1 = (const float*)d_in[7];
    const float* We1 = (const float*)d_in[8];
    const float* att1 = (const float*)d_in[9];
    const float* bias1 = (const float*)d_in[10];
    const float* Wl2 = (const float*)d_in[11];
    const float* bl2 = (const float*)d_in[12];
    const float* Wr2 = (const float*)d_in[13];
    const float* br2 = (const float*)d_in[14];
    const float* We2 = (const float*)d_in[15];
    const float* att2 = (const float*)d_in[16];
    const float* bias2 = (const float*)d_in[17];
    const float* W1 = (const float*)d_in[18];
    const float* c1 = (const float*)d_in[19];
    const float* W2 = (const float*)d_in[20];
    const float* c2 = (const float*)d_in[21];
    const float* W3 = (const float*)d_in[22];
    const float* c3 = (const float*)d_in[23];
    const float* W4 = (const float*)d_in[24];
    const float* c4 = (const float*)d_in[25];
    const float* W5 = (const float*)d_in[26];
    const float* c5 = (const float*)d_in[27];
    const float* W6 = (const float*)d_in[28];
    const float* c6 = (const float*)d_in[29];

    const int N = in_sizes[0] / 128;
    const int E = in_sizes[1] / 2;
    const int* srcs = eidx;
    const int* dsts = eidx + E;

    char* p = (char*)d_ws;
    auto alloc = [&](size_t bytes) -> char* {
        char* r = p;
        p += (bytes + 255) & ~(size_t)255;
        return r;
    };
    int*      deg     = (int*)alloc((size_t)N * 4);
    int*      row_ptr = (int*)alloc((size_t)(N + 1) * 4);
    int*      woff    = (int*)alloc((size_t)N * 4);
    int*      cidx    = (int*)alloc((size_t)E * 4);
    int*      incl    = (int*)alloc((size_t)N * 4);
    int*      bsum    = (int*)alloc(64 * 4);
    float*    easum   = (float*)alloc((size_t)N * 32 * 4);
    float*    xl      = (float*)alloc((size_t)N * 192 * 4);
    float*    xr      = (float*)alloc((size_t)N * 192 * 4);
    float*    h1      = (float*)alloc((size_t)N * 128 * 4);
    float*    h2      = (float*)alloc((size_t)N * 192 * 4);
    float*    alpha   = (float*)alloc((size_t)E * 3 * 4);
    float*    aself   = (float*)alloc((size_t)N * 3 * 4);
    unsigned* amax1   = (unsigned*)alloc((size_t)N * 2 * 4);
    unsigned* amax2   = (unsigned*)alloc((size_t)N * 3 * 4);
    float*    gp      = (float*)alloc(8 * 192 * 4);

    hipMemsetAsync(deg, 0, (size_t)N * 4, stream);
    hipMemsetAsync(easum, 0, (size_t)N * 32 * 4, stream);
    hipMemsetAsync(amax1, 0, (size_t)N * 2 * 4, stream);
    hipMemsetAsync(amax2, 0, (size_t)N * 3 * 4, stream);
    hipMemsetAsync(gp, 0, 8 * 192 * 4, stream);

    // CSR build
    const int nb = (N + 2047) / 2048;
    k_deg<<<(E + 255) / 256, 256, 0, stream>>>(dsts, E, deg);
    k_scan1<<<nb, 256, 0, stream>>>(deg, N, incl, bsum);
    k_scan2<<<1, 64, 0, stream>>>(bsum, nb);
    k_scan3<<<(N + 255) / 256, 256, 0, stream>>>(incl, deg, bsum, N, row_ptr, woff);
    k_scatter<<<(E + 255) / 256, 256, 0, stream>>>(dsts, E, woff, cidx);
    k_easum<<<((E * 32) + 255) / 256, 256, 0, stream>>>(ea, dsts, E, easum);

    const int mt = (N + 63) / 64;             // GEMM row tiles
    const int ablk = ((E + 7) / 8 + 3) / 4;   // k_alpha blocks
    const int nblk = (N + 3) / 4;             // node-parallel blocks

    // conv1: H=2, HC=128
    k_xw<128><<<dim3(mt, 2), 256, 0, stream>>>(x, N, Wl1, bl1, Wr1, br1, xl, xr);
    k_selfalpha<2><<<nblk, 256, 0, stream>>>(xl, xr, easum, deg, We1, att1, N, aself, amax1);
    k_alpha<2><<<ablk, 256, 0, stream>>>(xl, xr, ea, srcs, dsts, E, We1, att1, alpha, amax1);
    k_aggr<2, true><<<nblk, 256, 0, stream>>>(xl, srcs, cidx, row_ptr, alpha, aself, amax1,
                                              bias1, N, h1);
    // conv2: H=3, HC=192
    k_xw<192><<<dim3(mt, 3), 256, 0, stream>>>(h1, N, Wl2, bl2, Wr2, br2, xl, xr);
    k_selfalpha<3><<<nblk, 256, 0, stream>>>(xl, xr, easum, deg, We2, att2, N, aself, amax2);
    k_alpha<3><<<ablk, 256, 0, stream>>>(xl, xr, ea, srcs, dsts, E, We2, att2, alpha, amax2);
    k_aggr<3, true><<<nblk, 256, 0, stream>>>(xl, srcs, cidx, row_ptr, alpha, aself, amax2,
                                              bias2, N, h2);

    k_pool<<<(N + 127) / 128, 192, 0, stream>>>(h2, batch, N, gp);
    k_mlp<<<1, 256, 0, stream>>>(gp, W1, c1, W2, c2, W3, c3, W4, c4, W5, c5, W6, c6,
                                 (float*)d_out);
}